// Round 1
// baseline (4148.606 us; speedup 1.0000x reference)
//
#include <hip/hip_runtime.h>
#include <stdint.h>

// ---------------- problem constants ----------------
#define L_  6
#define B_  8
#define T_  512
#define C_  768
#define FC_ 3072
#define H_  12
#define DK_ 64
#define TP_ 514   // T + 2 zero-pad rows (row r holds token r-1)

typedef _Float16 half_t;
typedef half_t f16x8 __attribute__((ext_vector_type(8)));
typedef float  f32x4 __attribute__((ext_vector_type(4)));

static constexpr long alg(long x) { return (x + 255) & ~255L; }

// ---------------- workspace layout (bytes) ----------------
constexpr long SZ_W_B   = (long)L_ * C_ * C_ * 2;        // one proj weight set, fp16
constexpr long SZ_W1_B  = (long)L_ * 3 * FC_ * C_ * 2;   // repacked [L][3][FC][C]
constexpr long SZ_ACT_B = (long)B_ * TP_ * C_ * 2;       // padded token-major act fp16
constexpr long SZ_VT_B  = ((long)B_ * C_ * T_ + 65536) * 2; // v transposed + over-read pad
constexpr long SZ_H_B   = (long)B_ * TP_ * FC_ * 2;
constexpr long SZ_P_B   = (long)B_ * H_ * T_ * T_ * 2;
constexpr long SZ_XW_B  = (long)B_ * T_ * C_ * 4;        // fp32 master x

constexpr long O_WQ  = 0;
constexpr long O_WK  = O_WQ  + alg(SZ_W_B);
constexpr long O_WV  = O_WK  + alg(SZ_W_B);
constexpr long O_WO  = O_WV  + alg(SZ_W_B);
constexpr long O_W1  = O_WO  + alg(SZ_W_B);
constexpr long O_W2  = O_W1  + alg(SZ_W1_B);
constexpr long O_X   = O_W2  + alg(SZ_W1_B);
constexpr long O_Q   = O_X   + alg(SZ_ACT_B);
constexpr long O_K   = O_Q   + alg(SZ_ACT_B);
constexpr long O_ATT = O_K   + alg(SZ_ACT_B);
constexpr long O_VT  = O_ATT + alg(SZ_ACT_B);
constexpr long O_H   = O_VT  + alg(SZ_VT_B);
constexpr long O_P   = O_H   + alg(SZ_H_B);
constexpr long O_XW  = O_P   + alg(SZ_P_B);
constexpr long O_Y   = O_XW  + alg(SZ_XW_B);
constexpr long WS_NEED = O_Y + alg(SZ_XW_B);

// ---------------- async global->LDS (16B/lane, wave-uniform LDS base) ----------------
__device__ __forceinline__ void async_ld16(half_t* lds, const half_t* g) {
  __builtin_amdgcn_global_load_lds(
      (const __attribute__((address_space(1))) void*)g,
      (__attribute__((address_space(3))) void*)lds,
      16, 0, 0);
}

// ---------------- generic NT GEMM, 128x128 tile, BK=32, fp16 MFMA ----------------
// Out[m][n] = scale * ( sum_{s,k} A[(rowA+s)+m][k] * B[s][rowB+n][k] + bias[n] )
// A: row-major [.. , lda]; B: nshift slabs of row-major [N, ldb] at stride sBs.
// z-mapping: bz = z/hdiv, hz = z%hdiv; operand ptr += bz*s?z + hz*s?h.
struct GemmArgs {
  const half_t* A; const half_t* B; const float* bias; void* out;
  long lda, ldb, ldo;
  long sAz, sAh, sBz, sBh, sBs, sOz, sOh;
  int hdiv, rowA, rowB, Kc, nshift, mode, relu, nlim;
  float scale;
};

__global__ __launch_bounds__(256) void gemm_nt(GemmArgs g) {
  __shared__ half_t As[128 * 32];
  __shared__ half_t Bs[128 * 32];
  const int tid  = threadIdx.x;
  const int lane = tid & 63;
  const int wv   = tid >> 6;
  const int wm   = (wv >> 1) * 64;
  const int wn   = (wv & 1) * 64;
  const int z    = blockIdx.z;
  const int bz   = z / g.hdiv, hz = z % g.hdiv;
  const half_t* Ab = g.A + (long)bz * g.sAz + (long)hz * g.sAh;
  const half_t* Bb = g.B + (long)bz * g.sBz + (long)hz * g.sBh;
  const long m0 = (long)blockIdx.x * 128;
  const long n0 = (long)blockIdx.y * 128;

  const int srow = lane >> 2;        // 0..15
  const int scol = (lane & 3) * 8;   // k element offset (8 halves = 16B)
  half_t* AsW = As + (wv * 32) * 32; // this wave's 32-row LDS chunk
  half_t* BsW = Bs + (wv * 32) * 32;

  f32x4 acc[4][4];
#pragma unroll
  for (int i = 0; i < 4; ++i)
#pragma unroll
    for (int j = 0; j < 4; ++j) acc[i][j] = f32x4{0.f, 0.f, 0.f, 0.f};

  for (int s = 0; s < g.nshift; ++s) {
    const half_t* Arow = Ab + (long)(g.rowA + s) * g.lda + m0 * g.lda;
    const half_t* Brow = Bb + (long)s * g.sBs + (g.rowB + n0) * g.ldb;
    for (int kb = 0; kb < g.Kc; kb += 32) {
#pragma unroll
      for (int i = 0; i < 2; ++i) {
        async_ld16(AsW + i * 16 * 32,
                   Arow + (long)(wv * 32 + i * 16 + srow) * g.lda + kb + scol);
        async_ld16(BsW + i * 16 * 32,
                   Brow + (long)(wv * 32 + i * 16 + srow) * g.ldb + kb + scol);
      }
      __syncthreads();
      f16x8 af[4], bfr[4];
#pragma unroll
      for (int f = 0; f < 4; ++f) {
        af[f]  = *(const f16x8*)(As + (wm + f * 16 + (lane & 15)) * 32 + (lane >> 4) * 8);
        bfr[f] = *(const f16x8*)(Bs + (wn + f * 16 + (lane & 15)) * 32 + (lane >> 4) * 8);
      }
#pragma unroll
      for (int fm = 0; fm < 4; ++fm)
#pragma unroll
        for (int fn = 0; fn < 4; ++fn)
          acc[fm][fn] = __builtin_amdgcn_mfma_f32_16x16x32_f16(af[fm], bfr[fn], acc[fm][fn], 0, 0, 0);
      __syncthreads();
    }
  }

  const int col = lane & 15, quad = lane >> 4;
  const long obase = (long)bz * g.sOz + (long)hz * g.sOh;
#pragma unroll
  for (int fm = 0; fm < 4; ++fm) {
#pragma unroll
    for (int fn = 0; fn < 4; ++fn) {
      int n = (int)n0 + wn + fn * 16 + col;
      if (n >= g.nlim) continue;
      float bia = g.bias ? g.bias[n] : 0.f;
#pragma unroll
      for (int i = 0; i < 4; ++i) {
        long m = m0 + wm + fm * 16 + quad * 4 + i;
        float v = (acc[fm][fn][i] + bia) * g.scale;
        if (g.relu) v = fmaxf(v, 0.f);
        if (g.mode == 0)      ((float*)g.out)[obase + m * g.ldo + n] = v;
        else if (g.mode == 1) ((half_t*)g.out)[obase + m * g.ldo + n] = (half_t)v;
        else                  ((half_t*)g.out)[obase + (long)n * g.ldo + m] = (half_t)v;
      }
    }
  }
}

// ---------------- softmax with banded relative-k logits, in-place on p ----------------
__global__ __launch_bounds__(256) void softmax_rel(half_t* p, const half_t* q, const float* erk) {
  const int t = blockIdx.x, h = blockIdx.y, b = blockIdx.z;
  __shared__ float relv[9];
  __shared__ float red[4];
  const int tid = threadIdx.x;
  if (tid < 64) {  // wave 0: 9 banded logits = (qs[t] . erk[r])
    float qv = (float)q[((long)b * TP_ + t + 1) * C_ + h * 64 + tid];
#pragma unroll
    for (int r = 0; r < 9; ++r) {
      float pr = qv * erk[r * 64 + tid];
#pragma unroll
      for (int off = 32; off; off >>= 1) pr += __shfl_xor(pr, off);
      if (tid == 0) relv[r] = pr;
    }
  }
  __syncthreads();
  half_t* row = p + ((long)(b * H_ + h) * T_ + t) * T_;
  float v0 = (float)row[tid], v1 = (float)row[tid + 256];
  int d0 = tid - t + 4, d1 = tid + 256 - t + 4;
  if (d0 >= 0 && d0 < 9) v0 += relv[d0];
  if (d1 >= 0 && d1 < 9) v1 += relv[d1];
  float mx = fmaxf(v0, v1);
#pragma unroll
  for (int off = 32; off; off >>= 1) mx = fmaxf(mx, __shfl_xor(mx, off));
  const int w = tid >> 6;
  if ((tid & 63) == 0) red[w] = mx;
  __syncthreads();
  mx = fmaxf(fmaxf(red[0], red[1]), fmaxf(red[2], red[3]));
  float e0 = __expf(v0 - mx), e1 = __expf(v1 - mx);
  float sm = e0 + e1;
#pragma unroll
  for (int off = 32; off; off >>= 1) sm += __shfl_xor(sm, off);
  __syncthreads();
  if ((tid & 63) == 0) red[w] = sm;
  __syncthreads();
  float inv = 1.f / (red[0] + red[1] + red[2] + red[3]);
  row[tid]       = (half_t)(e0 * inv);
  row[tid + 256] = (half_t)(e1 * inv);
}

// ---------------- banded p @ rel_v add into attention output ----------------
__global__ __launch_bounds__(256) void add_rel_v(half_t* attn, const half_t* p, const float* erv) {
  const int w = threadIdx.x >> 6, lane = threadIdx.x & 63;
  const int t = blockIdx.x * 4 + w, h = blockIdx.y, b = blockIdx.z;
  const half_t* prow = p + ((long)(b * H_ + h) * T_ + t) * T_;
  float acc = 0.f;
#pragma unroll
  for (int r = 0; r < 9; ++r) {
    int s = t + r - 4;
    if (s >= 0 && s < T_) acc += (float)prow[s] * erv[r * 64 + lane];
  }
  long idx = ((long)b * TP_ + t + 1) * C_ + h * 64 + lane;
  attn[idx] = (half_t)((float)attn[idx] + acc);
}

// ---------------- residual + LayerNorm over C; writes fp32 master and fp16 copy ----------------
__global__ __launch_bounds__(256) void ln_res(float* xw, const float* y,
                                              const float* gamma, const float* beta, half_t* xbf) {
  __shared__ float redA[4], redB[4];
  const int row = blockIdx.x;           // b*T + t
  const int b = row >> 9, t = row & 511;
  const long base = (long)row * C_;
  float v[3]; float sum = 0.f, sq = 0.f;
#pragma unroll
  for (int i = 0; i < 3; ++i) {
    int c = threadIdx.x + i * 256;
    float s = xw[base + c] + y[base + c];
    v[i] = s; sum += s; sq += s * s;
  }
#pragma unroll
  for (int off = 32; off; off >>= 1) { sum += __shfl_xor(sum, off); sq += __shfl_xor(sq, off); }
  const int w = threadIdx.x >> 6;
  if ((threadIdx.x & 63) == 0) { redA[w] = sum; redB[w] = sq; }
  __syncthreads();
  sum = redA[0] + redA[1] + redA[2] + redA[3];
  sq  = redB[0] + redB[1] + redB[2] + redB[3];
  float mean = sum * (1.f / C_);
  float var  = sq * (1.f / C_) - mean * mean;
  float rstd = rsqrtf(var + 1e-5f);
  const long bb = ((long)b * TP_ + t + 1) * C_;
#pragma unroll
  for (int i = 0; i < 3; ++i) {
    int c = threadIdx.x + i * 256;
    float o = (v[i] - mean) * rstd * gamma[c] + beta[c];
    xw[base + c] = o;
    xbf[bb + c] = (half_t)o;
  }
}

// ---------------- transposes in/out ([B][C][T] <-> token-major) ----------------
__global__ __launch_bounds__(256) void transpose_in(const float* xin, const float* mask,
                                                    float* xw, half_t* xbf) {
  __shared__ float tl[32][33];
  const int b = blockIdx.z, t0 = blockIdx.x * 32, c0 = blockIdx.y * 32;
  const int tx = threadIdx.x, ty = threadIdx.y;
#pragma unroll
  for (int j = 0; j < 4; ++j) {
    int c = c0 + ty + j * 8;
    tl[ty + j * 8][tx] = xin[((long)b * C_ + c) * T_ + t0 + tx] * mask[(long)b * T_ + t0 + tx];
  }
  __syncthreads();
#pragma unroll
  for (int j = 0; j < 4; ++j) {
    int t = t0 + ty + j * 8;
    float v = tl[tx][ty + j * 8];   // = xin[c0+tx][t]
    xw[((long)b * T_ + t) * C_ + c0 + tx] = v;
    xbf[((long)b * TP_ + t + 1) * C_ + c0 + tx] = (half_t)v;
  }
}

__global__ __launch_bounds__(256) void transpose_out(const float* xw, const float* mask, float* out) {
  __shared__ float tl[32][33];
  const int b = blockIdx.z, t0 = blockIdx.x * 32, c0 = blockIdx.y * 32;
  const int tx = threadIdx.x, ty = threadIdx.y;
#pragma unroll
  for (int j = 0; j < 4; ++j) {
    int t = t0 + ty + j * 8;
    tl[ty + j * 8][tx] = xw[((long)b * T_ + t) * C_ + c0 + tx];
  }
  __syncthreads();
#pragma unroll
  for (int j = 0; j < 4; ++j) {
    int c = c0 + ty + j * 8;
    out[((long)b * C_ + c) * T_ + t0 + tx] = tl[tx][ty + j * 8] * mask[(long)b * T_ + t0 + tx];
  }
}

// ---------------- weight conversion / repack ----------------
__global__ void cvt_f2h(const float* in, half_t* out, long n) {
  long i = (long)blockIdx.x * 256 + threadIdx.x;
  if (i < n) out[i] = (half_t)in[i];
}
__global__ void cvt_w1(const float* in, half_t* out) {  // [L][FC][C][3] -> [L][3][FC][C]
  long i = (long)blockIdx.x * 256 + threadIdx.x;
  const long n = (long)L_ * 3 * FC_ * C_;
  if (i >= n) return;
  long c = i % C_, f = (i / C_) % FC_, k = (i / ((long)C_ * FC_)) % 3, l = i / (3L * C_ * FC_);
  out[i] = (half_t)in[((l * FC_ + f) * C_ + c) * 3 + k];
}
__global__ void cvt_w2(const float* in, half_t* out) {  // [L][C][FC][3] -> [L][3][C][FC]
  long i = (long)blockIdx.x * 256 + threadIdx.x;
  const long n = (long)L_ * 3 * C_ * FC_;
  if (i >= n) return;
  long f = i % FC_, c = (i / FC_) % C_, k = (i / ((long)FC_ * C_)) % 3, l = i / (3L * FC_ * C_);
  out[i] = (half_t)in[((l * C_ + c) * FC_ + f) * 3 + k];
}
__global__ void zero_pads(half_t* xbf, half_t* hbf) {
  long i = (long)blockIdx.x * 256 + threadIdx.x;
  const long nx = (long)B_ * 2 * C_, nh = (long)B_ * 2 * FC_;
  if (i < nx) {
    long b = i / (2 * C_), r = (i / C_) % 2, c = i % C_;
    xbf[(b * TP_ + (r ? TP_ - 1 : 0)) * C_ + c] = (half_t)0.f;
  } else if (i < nx + nh) {
    long j = i - nx;
    long b = j / (2 * FC_), r = (j / FC_) % 2, f = j % FC_;
    hbf[(b * TP_ + (r ? TP_ - 1 : 0)) * FC_ + f] = (half_t)0.f;
  }
}

// ---------------- host orchestration ----------------
extern "C" void kernel_launch(void* const* d_in, const int* in_sizes, int n_in,
                              void* d_out, int out_size, void* d_ws, size_t ws_size,
                              hipStream_t stream) {
  if ((long)ws_size < WS_NEED) return;  // insufficient scratch; fail cleanly

  const float* x_in = (const float*)d_in[0];
  const float* mask = (const float*)d_in[1];
  const float* Wq = (const float*)d_in[2];  const float* bq = (const float*)d_in[3];
  const float* Wk = (const float*)d_in[4];  const float* bk = (const float*)d_in[5];
  const float* Wv = (const float*)d_in[6];  const float* bv = (const float*)d_in[7];
  const float* Wo = (const float*)d_in[8];  const float* bo = (const float*)d_in[9];
  const float* erk = (const float*)d_in[10];
  const float* erv = (const float*)d_in[11];
  const float* W1 = (const float*)d_in[12]; const float* b1 = (const float*)d_in[13];
  const float* W2 = (const float*)d_in[14]; const float* b2 = (const float*)d_in[15];
  const float* g1 = (const float*)d_in[16]; const float* be1 = (const float*)d_in[17];
  const float* g2 = (const float*)d_in[18]; const float* be2 = (const float*)d_in[19];

  char* w = (char*)d_ws;
  half_t* wq_h = (half_t*)(w + O_WQ);
  half_t* wk_h = (half_t*)(w + O_WK);
  half_t* wv_h = (half_t*)(w + O_WV);
  half_t* wo_h = (half_t*)(w + O_WO);
  half_t* w1_h = (half_t*)(w + O_W1);
  half_t* w2_h = (half_t*)(w + O_W2);
  half_t* x_h  = (half_t*)(w + O_X);
  half_t* q_h  = (half_t*)(w + O_Q);
  half_t* k_h  = (half_t*)(w + O_K);
  half_t* at_h = (half_t*)(w + O_ATT);
  half_t* vt_h = (half_t*)(w + O_VT);
  half_t* h_h  = (half_t*)(w + O_H);
  half_t* p_h  = (half_t*)(w + O_P);
  float*  xw   = (float*)(w + O_XW);
  float*  yb   = (float*)(w + O_Y);

  const long NW  = (long)L_ * C_ * C_;
  const long NW1 = (long)L_ * 3 * FC_ * C_;
  cvt_f2h<<<dim3((NW + 255) / 256), 256, 0, stream>>>(Wq, wq_h, NW);
  cvt_f2h<<<dim3((NW + 255) / 256), 256, 0, stream>>>(Wk, wk_h, NW);
  cvt_f2h<<<dim3((NW + 255) / 256), 256, 0, stream>>>(Wv, wv_h, NW);
  cvt_f2h<<<dim3((NW + 255) / 256), 256, 0, stream>>>(Wo, wo_h, NW);
  cvt_w1<<<dim3((NW1 + 255) / 256), 256, 0, stream>>>(W1, w1_h);
  cvt_w2<<<dim3((NW1 + 255) / 256), 256, 0, stream>>>(W2, w2_h);
  transpose_in<<<dim3(16, 24, 8), dim3(32, 8), 0, stream>>>(x_in, mask, xw, x_h);
  zero_pads<<<dim3((B_ * 2 * (C_ + FC_) + 255) / 256), 256, 0, stream>>>(x_h, h_h);

  for (int l = 0; l < L_; ++l) {
    const half_t* wql = wq_h + (long)l * C_ * C_;
    const half_t* wkl = wk_h + (long)l * C_ * C_;
    const half_t* wvl = wv_h + (long)l * C_ * C_;
    const half_t* wol = wo_h + (long)l * C_ * C_;
    const half_t* w1l = w1_h + (long)l * 3 * FC_ * C_;
    const half_t* w2l = w2_h + (long)l * 3 * C_ * FC_;

    GemmArgs a;
    // ---- Q projection (pre-scaled by 1/sqrt(DK)) ----
    a.A = x_h; a.lda = C_; a.rowA = 1; a.sAz = (long)TP_ * C_; a.sAh = 0;
    a.B = wql; a.ldb = C_; a.rowB = 0; a.sBz = 0; a.sBh = 0; a.sBs = 0;
    a.Kc = C_; a.nshift = 1; a.bias = bq + l * C_; a.scale = 0.125f; a.relu = 0;
    a.out = (void*)(q_h + C_); a.mode = 1; a.ldo = C_; a.sOz = (long)TP_ * C_; a.sOh = 0;
    a.hdiv = 1; a.nlim = C_;
    gemm_nt<<<dim3(4, 6, 8), 256, 0, stream>>>(a);
    // ---- K projection ----
    a.B = wkl; a.bias = bk + l * C_; a.scale = 1.f; a.out = (void*)(k_h + C_);
    gemm_nt<<<dim3(4, 6, 8), 256, 0, stream>>>(a);
    // ---- V projection, written transposed per head: v_t[b][c][t] ----
    a.B = wvl; a.bias = bv + l * C_; a.out = (void*)vt_h; a.mode = 2;
    a.ldo = T_; a.sOz = (long)C_ * T_; a.sOh = 0;
    gemm_nt<<<dim3(4, 6, 8), 256, 0, stream>>>(a);
    // ---- scores = qs k^T per (b,h) ----
    a.A = q_h; a.lda = C_; a.rowA = 1; a.sAz = (long)TP_ * C_; a.sAh = 64;
    a.B = k_h; a.ldb = C_; a.rowB = 1; a.sBz = (long)TP_ * C_; a.sBh = 64; a.sBs = 0;
    a.Kc = 64; a.nshift = 1; a.bias = nullptr; a.scale = 1.f; a.relu = 0;
    a.out = (void*)p_h; a.mode = 1; a.ldo = T_;
    a.sOz = (long)H_ * T_ * T_; a.sOh = (long)T_ * T_;
    a.hdiv = H_; a.nlim = T_;
    gemm_nt<<<dim3(4, 4, 96), 256, 0, stream>>>(a);
    // ---- softmax with banded rel-k logits (in place) ----
    softmax_rel<<<dim3(512, 12, 8), 256, 0, stream>>>(p_h, q_h, erk);
    // ---- out = p @ v per (b,h) ----
    a.A = p_h; a.lda = T_; a.rowA = 0; a.sAz = (long)H_ * T_ * T_; a.sAh = (long)T_ * T_;
    a.B = vt_h; a.ldb = T_; a.rowB = 0; a.sBz = (long)C_ * T_; a.sBh = 64L * T_; a.sBs = 0;
    a.Kc = T_; a.nshift = 1; a.bias = nullptr; a.scale = 1.f; a.relu = 0;
    a.out = (void*)(at_h + C_); a.mode = 1; a.ldo = C_;
    a.sOz = (long)TP_ * C_; a.sOh = 64;
    a.hdiv = H_; a.nlim = 64;
    gemm_nt<<<dim3(4, 1, 96), 256, 0, stream>>>(a);
    // ---- banded p @ rel_v add ----
    add_rel_v<<<dim3(128, 12, 8), 256, 0, stream>>>(at_h, p_h, erv);
    // ---- Wo projection -> y (fp32) ----
    a.A = at_h; a.lda = C_; a.rowA = 1; a.sAz = (long)TP_ * C_; a.sAh = 0;
    a.B = wol; a.ldb = C_; a.rowB = 0; a.sBz = 0; a.sBh = 0; a.sBs = 0;
    a.Kc = C_; a.nshift = 1; a.bias = bo + l * C_; a.scale = 1.f; a.relu = 0;
    a.out = (void*)yb; a.mode = 0; a.ldo = C_; a.sOz = (long)T_ * C_; a.sOh = 0;
    a.hdiv = 1; a.nlim = C_;
    gemm_nt<<<dim3(4, 6, 8), 256, 0, stream>>>(a);
    // ---- LN1 ----
    ln_res<<<dim3(B_ * T_), 256, 0, stream>>>(xw, yb, g1 + l * C_, be1 + l * C_, x_h);
    // ---- conv FFN layer 1 (3-shift fused GEMM, relu) ----
    a.A = x_h; a.lda = C_; a.rowA = 0; a.sAz = (long)TP_ * C_; a.sAh = 0;
    a.B = w1l; a.ldb = C_; a.rowB = 0; a.sBz = 0; a.sBh = 0; a.sBs = (long)FC_ * C_;
    a.Kc = C_; a.nshift = 3; a.bias = b1 + l * FC_; a.scale = 1.f; a.relu = 1;
    a.out = (void*)(h_h + FC_); a.mode = 1; a.ldo = FC_; a.sOz = (long)TP_ * FC_; a.sOh = 0;
    a.hdiv = 1; a.nlim = FC_;
    gemm_nt<<<dim3(4, 24, 8), 256, 0, stream>>>(a);
    // ---- conv FFN layer 2 ----
    a.A = h_h; a.lda = FC_; a.rowA = 0; a.sAz = (long)TP_ * FC_; a.sAh = 0;
    a.B = w2l; a.ldb = FC_; a.rowB = 0; a.sBz = 0; a.sBh = 0; a.sBs = (long)C_ * FC_;
    a.Kc = FC_; a.nshift = 3; a.bias = b2 + l * C_; a.scale = 1.f; a.relu = 0;
    a.out = (void*)yb; a.mode = 0; a.ldo = C_; a.sOz = (long)T_ * C_; a.sOh = 0;
    a.hdiv = 1; a.nlim = C_;
    gemm_nt<<<dim3(4, 6, 8), 256, 0, stream>>>(a);
    // ---- LN2 ----
    ln_res<<<dim3(B_ * T_), 256, 0, stream>>>(xw, yb, g2 + l * C_, be2 + l * C_, x_h);
  }

  transpose_out<<<dim3(16, 24, 8), dim3(32, 8), 0, stream>>>(xw, mask, (float*)d_out);
}

// Round 2
// 3111.178 us; speedup vs baseline: 1.3335x; 1.3335x over previous
//
#include <hip/hip_runtime.h>
#include <stdint.h>

// ---------------- problem constants ----------------
#define L_  6
#define B_  8
#define T_  512
#define C_  768
#define FC_ 3072
#define H_  12
#define DK_ 64
#define TP_ 514   // T + 2 zero-pad rows (row r holds token r-1)
#define QKV_ (3 * C_)

typedef _Float16 half_t;
typedef half_t f16x8 __attribute__((ext_vector_type(8)));
typedef float  f32x4 __attribute__((ext_vector_type(4)));

static constexpr long alg(long x) { return (x + 255) & ~255L; }
constexpr long SLAB = (long)B_ * T_ * C_;   // fp32 partial slab elements

// ---------------- workspace layout (bytes) ----------------
constexpr long SZ_WQKV_B = (long)L_ * QKV_ * C_ * 2;
constexpr long SZ_WO_B   = (long)L_ * C_ * C_ * 2;
constexpr long SZ_W1_B   = (long)L_ * 3 * FC_ * C_ * 2;  // repacked [L][3][FC][C]
constexpr long SZ_BQ_B   = (long)L_ * QKV_ * 4;
constexpr long SZ_ACT_B  = (long)B_ * TP_ * C_ * 2;
constexpr long SZ_VT_B   = ((long)B_ * C_ * T_ + 65536) * 2;
constexpr long SZ_H_B    = (long)B_ * TP_ * FC_ * 2;
constexpr long SZ_P_B    = (long)B_ * H_ * T_ * T_ * 2;
constexpr long SZ_XW_B   = SLAB * 4;
constexpr long SZ_Y_B    = 4 * SLAB * 4;                 // 4 fp32 partial slabs

constexpr long O_WQKV = 0;
constexpr long O_WO  = O_WQKV + alg(SZ_WQKV_B);
constexpr long O_W1  = O_WO   + alg(SZ_WO_B);
constexpr long O_W2  = O_W1   + alg(SZ_W1_B);
constexpr long O_BQ  = O_W2   + alg(SZ_W1_B);
constexpr long O_X   = O_BQ   + alg(SZ_BQ_B);
constexpr long O_Q   = O_X    + alg(SZ_ACT_B);
constexpr long O_K   = O_Q    + alg(SZ_ACT_B);
constexpr long O_ATT = O_K    + alg(SZ_ACT_B);
constexpr long O_VT  = O_ATT  + alg(SZ_ACT_B);
constexpr long O_H   = O_VT   + alg(SZ_VT_B);
constexpr long O_P   = O_H    + alg(SZ_H_B);
constexpr long O_XW  = O_P    + alg(SZ_P_B);
constexpr long O_Y   = O_XW   + alg(SZ_XW_B);
constexpr long WS_NEED = O_Y + alg(SZ_Y_B);

// ---------------- async global->LDS (16B/lane, wave-uniform LDS base) ----------------
__device__ __forceinline__ void async_ld16(half_t* lds, const half_t* g) {
  __builtin_amdgcn_global_load_lds(
      (const __attribute__((address_space(1))) void*)g,
      (__attribute__((address_space(3))) void*)lds,
      16, 0, 0);
}

// ---------------- generic NT GEMM, 128x128 tile, BK=32, fp16 MFMA, split-K ----------------
// LDS layout swizzle: fragment (row r, k-quad kq) of a 32-row chunk lives at
// slot r*4 + ((kq + r) & 3) (16B slots) -> breaks same-bank-group aliasing of
// the 4 k-quads while keeping the global_load_lds lane-ordered destination.
struct GemmArgs {
  const half_t* A; const half_t* B; const float* bias;
  void* out; void* out2; void* out3;
  long lda, ldb, ldo;
  long sAz, sAh, sBz, sBh, sBs, sOz, sOh, sPart;
  int hdiv, rowA, rowB, Kc, nshift, ksplit, mode, relu, nlim;
};

__global__ __launch_bounds__(256) void gemm_nt(GemmArgs g) {
  __shared__ half_t As[128 * 32];
  __shared__ half_t Bs[128 * 32];
  const int tid  = threadIdx.x;
  const int lane = tid & 63;
  const int wv   = tid >> 6;
  const int wm   = (wv >> 1) * 64;
  const int wn   = (wv & 1) * 64;
  const int zz   = blockIdx.z;
  const int ks   = zz % g.ksplit;
  const int z    = zz / g.ksplit;
  const int bz   = z / g.hdiv, hz = z % g.hdiv;
  const half_t* Ab = g.A + (long)bz * g.sAz + (long)hz * g.sAh;
  const half_t* Bb = g.B + (long)bz * g.sBz + (long)hz * g.sBh;
  const long m0 = (long)blockIdx.x * 128;
  const long n0 = (long)blockIdx.y * 128;

  // staging: lane -> slot (i*64+lane); row = slot>>2, kq = ((slot&3)-(row&3))&3
  const int srow = lane >> 2;
  const int scol = ((((lane & 3) - (srow & 3)) & 3)) * 8;
  half_t* AsW = As + wv * 1024;
  half_t* BsW = Bs + wv * 1024;

  f32x4 acc[4][4];
#pragma unroll
  for (int i = 0; i < 4; ++i)
#pragma unroll
    for (int j = 0; j < 4; ++j) acc[i][j] = f32x4{0.f, 0.f, 0.f, 0.f};

  const int nkb = g.Kc >> 5;                 // 32-wide k-steps per shift
  const int nIter = g.nshift * nkb;
  const int chunk = (nIter + g.ksplit - 1) / g.ksplit;
  int it = ks * chunk;
  const int itEnd0 = it + chunk;
  const int itEnd = itEnd0 < nIter ? itEnd0 : nIter;

  const int kqr = lane >> 4;                 // read k-quad
  while (it < itEnd) {
    const int s = it / nkb;
    int kbi = it - s * nkb;
    int kbiEnd = kbi + (itEnd - it);
    if (kbiEnd > nkb) kbiEnd = nkb;
    it += kbiEnd - kbi;
    const half_t* Arow = Ab + ((long)(g.rowA + s) + m0) * g.lda;
    const half_t* Brow = Bb + (long)s * g.sBs + (g.rowB + n0) * g.ldb;
    for (; kbi < kbiEnd; ++kbi) {
      const int kb = kbi << 5;
#pragma unroll
      for (int i = 0; i < 2; ++i) {
        async_ld16(AsW + i * 512,
                   Arow + (long)(wv * 32 + i * 16 + srow) * g.lda + kb + scol);
        async_ld16(BsW + i * 512,
                   Brow + (long)(wv * 32 + i * 16 + srow) * g.ldb + kb + scol);
      }
      __syncthreads();
      f16x8 af[4], bfr[4];
#pragma unroll
      for (int f = 0; f < 4; ++f) {
        int rA = wm + f * 16 + (lane & 15);
        int rB = wn + f * 16 + (lane & 15);
        af[f]  = *(const f16x8*)(As + (rA >> 5) * 1024 + (rA & 31) * 32 + ((kqr + rA) & 3) * 8);
        bfr[f] = *(const f16x8*)(Bs + (rB >> 5) * 1024 + (rB & 31) * 32 + ((kqr + rB) & 3) * 8);
      }
#pragma unroll
      for (int fm = 0; fm < 4; ++fm)
#pragma unroll
        for (int fn = 0; fn < 4; ++fn)
          acc[fm][fn] = __builtin_amdgcn_mfma_f32_16x16x32_f16(af[fm], bfr[fn], acc[fm][fn], 0, 0, 0);
      __syncthreads();
    }
  }

  const int col = lane & 15, quad = lane >> 4;
  const long obase = (long)bz * g.sOz + (long)hz * g.sOh + (long)ks * g.sPart;
#pragma unroll
  for (int fm = 0; fm < 4; ++fm) {
#pragma unroll
    for (int fn = 0; fn < 4; ++fn) {
      int n = (int)n0 + wn + fn * 16 + col;
      if (n >= g.nlim) continue;
      float bia = (g.bias && ks == 0) ? g.bias[n] : 0.f;
#pragma unroll
      for (int i = 0; i < 4; ++i) {
        long m = m0 + wm + fm * 16 + quad * 4 + i;
        float v = acc[fm][fn][i] + bia;
        if (g.relu) v = fmaxf(v, 0.f);
        if (g.mode == 0) {
          ((float*)g.out)[obase + m * g.ldo + n] = v;
        } else if (g.mode == 1) {
          ((half_t*)g.out)[obase + m * g.ldo + n] = (half_t)v;
        } else {  // mode 3: fused QKV router
          int seg = n / C_, nn = n - seg * C_;
          if (seg == 2)
            ((half_t*)g.out3)[((long)bz * C_ + nn) * T_ + m] = (half_t)v;
          else {
            half_t* dstb = seg ? (half_t*)g.out2 : (half_t*)g.out;
            dstb[((long)bz * TP_ + 1 + m) * C_ + nn] = (half_t)v;
          }
        }
      }
    }
  }
}

// ---------------- softmax with banded relative-k logits, in-place on p ----------------
__global__ __launch_bounds__(256) void softmax_rel(half_t* p, const half_t* q, const float* erk) {
  const int t = blockIdx.x, h = blockIdx.y, b = blockIdx.z;
  __shared__ float relv[9];
  __shared__ float red[4];
  const int tid = threadIdx.x;
  if (tid < 64) {
    float qv = (float)q[((long)b * TP_ + t + 1) * C_ + h * 64 + tid];
#pragma unroll
    for (int r = 0; r < 9; ++r) {
      float pr = qv * erk[r * 64 + tid];
#pragma unroll
      for (int off = 32; off; off >>= 1) pr += __shfl_xor(pr, off);
      if (tid == 0) relv[r] = pr;
    }
  }
  __syncthreads();
  half_t* row = p + ((long)(b * H_ + h) * T_ + t) * T_;
  float v0 = (float)row[tid], v1 = (float)row[tid + 256];
  int d0 = tid - t + 4, d1 = tid + 256 - t + 4;
  if (d0 >= 0 && d0 < 9) v0 += relv[d0];
  if (d1 >= 0 && d1 < 9) v1 += relv[d1];
  float mx = fmaxf(v0, v1);
#pragma unroll
  for (int off = 32; off; off >>= 1) mx = fmaxf(mx, __shfl_xor(mx, off));
  const int w = tid >> 6;
  if ((tid & 63) == 0) red[w] = mx;
  __syncthreads();
  mx = fmaxf(fmaxf(red[0], red[1]), fmaxf(red[2], red[3]));
  float e0 = __expf(v0 - mx), e1 = __expf(v1 - mx);
  float sm = e0 + e1;
#pragma unroll
  for (int off = 32; off; off >>= 1) sm += __shfl_xor(sm, off);
  __syncthreads();
  if ((tid & 63) == 0) red[w] = sm;
  __syncthreads();
  float inv = 1.f / (red[0] + red[1] + red[2] + red[3]);
  row[tid]       = (half_t)(e0 * inv);
  row[tid + 256] = (half_t)(e1 * inv);
}

// ---------------- PV-partials reduce + banded p @ rel_v -> attention fp16 ----------------
__global__ __launch_bounds__(256) void add_rel_v(half_t* attn, const float* pv,
                                                 const half_t* p, const float* erv) {
  const int w = threadIdx.x >> 6, lane = threadIdx.x & 63;
  const int t = blockIdx.x * 4 + w, h = blockIdx.y, b = blockIdx.z;
  const half_t* prow = p + ((long)(b * H_ + h) * T_ + t) * T_;
  long i32 = ((long)b * T_ + t) * C_ + h * 64 + lane;
  float acc = pv[i32] + pv[SLAB + i32];
#pragma unroll
  for (int r = 0; r < 9; ++r) {
    int s = t + r - 4;
    if (s >= 0 && s < T_) acc += (float)prow[s] * erv[r * 64 + lane];
  }
  attn[((long)b * TP_ + t + 1) * C_ + h * 64 + lane] = (half_t)acc;
}

// ---------------- 4-partial reduce + residual + LayerNorm ----------------
__global__ __launch_bounds__(256) void ln_res(float* xw, const float* yb,
                                              const float* gamma, const float* beta, half_t* xbf) {
  __shared__ float redA[4], redB[4];
  const int row = blockIdx.x;
  const int b = row >> 9, t = row & 511;
  const long base = (long)row * C_;
  float v[3]; float sum = 0.f, sq = 0.f;
#pragma unroll
  for (int i = 0; i < 3; ++i) {
    int c = threadIdx.x + i * 256;
    float s = xw[base + c];
#pragma unroll
    for (int j = 0; j < 4; ++j) s += yb[j * SLAB + base + c];
    v[i] = s; sum += s; sq += s * s;
  }
#pragma unroll
  for (int off = 32; off; off >>= 1) { sum += __shfl_xor(sum, off); sq += __shfl_xor(sq, off); }
  const int w = threadIdx.x >> 6;
  if ((threadIdx.x & 63) == 0) { redA[w] = sum; redB[w] = sq; }
  __syncthreads();
  sum = redA[0] + redA[1] + redA[2] + redA[3];
  sq  = redB[0] + redB[1] + redB[2] + redB[3];
  float mean = sum * (1.f / C_);
  float var  = sq * (1.f / C_) - mean * mean;
  float rstd = rsqrtf(var + 1e-5f);
  const long bb = ((long)b * TP_ + t + 1) * C_;
#pragma unroll
  for (int i = 0; i < 3; ++i) {
    int c = threadIdx.x + i * 256;
    float o = (v[i] - mean) * rstd * gamma[c] + beta[c];
    xw[base + c] = o;
    xbf[bb + c] = (half_t)o;
  }
}

// ---------------- transposes in/out ----------------
__global__ __launch_bounds__(256) void transpose_in(const float* xin, const float* mask,
                                                    float* xw, half_t* xbf) {
  __shared__ float tl[32][33];
  const int b = blockIdx.z, t0 = blockIdx.x * 32, c0 = blockIdx.y * 32;
  const int tx = threadIdx.x, ty = threadIdx.y;
#pragma unroll
  for (int j = 0; j < 4; ++j) {
    int c = c0 + ty + j * 8;
    tl[ty + j * 8][tx] = xin[((long)b * C_ + c) * T_ + t0 + tx] * mask[(long)b * T_ + t0 + tx];
  }
  __syncthreads();
#pragma unroll
  for (int j = 0; j < 4; ++j) {
    int t = t0 + ty + j * 8;
    float v = tl[tx][ty + j * 8];
    xw[((long)b * T_ + t) * C_ + c0 + tx] = v;
    xbf[((long)b * TP_ + t + 1) * C_ + c0 + tx] = (half_t)v;
  }
}

__global__ __launch_bounds__(256) void transpose_out(const float* xw, const float* mask, float* out) {
  __shared__ float tl[32][33];
  const int b = blockIdx.z, t0 = blockIdx.x * 32, c0 = blockIdx.y * 32;
  const int tx = threadIdx.x, ty = threadIdx.y;
#pragma unroll
  for (int j = 0; j < 4; ++j) {
    int t = t0 + ty + j * 8;
    tl[ty + j * 8][tx] = xw[((long)b * T_ + t) * C_ + c0 + tx];
  }
  __syncthreads();
#pragma unroll
  for (int j = 0; j < 4; ++j) {
    int c = c0 + ty + j * 8;
    out[((long)b * C_ + c) * T_ + t0 + tx] = tl[tx][ty + j * 8] * mask[(long)b * T_ + t0 + tx];
  }
}

// ---------------- weight conversion / repack ----------------
__global__ void cvt_f2h(const float* in, half_t* out, long n) {
  long i = (long)blockIdx.x * 256 + threadIdx.x;
  if (i < n) out[i] = (half_t)in[i];
}
// fused [L][2304][768] from Wq(*0.125)/Wk/Wv
__global__ void cvt_wqkv(const float* wq, const float* wk, const float* wv, half_t* out) {
  long i = (long)blockIdx.x * 256 + threadIdx.x;
  const long n = (long)L_ * QKV_ * C_;
  if (i >= n) return;
  long c = i % C_, o = (i / C_) % QKV_, l = i / ((long)QKV_ * C_);
  int seg = (int)(o / C_); long oo = o - (long)seg * C_;
  const float* src = seg == 0 ? wq : (seg == 1 ? wk : wv);
  float v = src[(l * C_ + oo) * C_ + c];
  out[i] = (half_t)(seg == 0 ? v * 0.125f : v);
}
__global__ void cvt_bqkv(const float* bq, const float* bk, const float* bv, float* out) {
  long i = (long)blockIdx.x * 256 + threadIdx.x;
  const long n = (long)L_ * QKV_;
  if (i >= n) return;
  long o = i % QKV_, l = i / QKV_;
  int seg = (int)(o / C_); long oo = o - (long)seg * C_;
  const float* src = seg == 0 ? bq : (seg == 1 ? bk : bv);
  float v = src[l * C_ + oo];
  out[i] = seg == 0 ? v * 0.125f : v;
}
__global__ void cvt_w1(const float* in, half_t* out) {  // [L][FC][C][3] -> [L][3][FC][C]
  long i = (long)blockIdx.x * 256 + threadIdx.x;
  const long n = (long)L_ * 3 * FC_ * C_;
  if (i >= n) return;
  long c = i % C_, f = (i / C_) % FC_, k = (i / ((long)C_ * FC_)) % 3, l = i / (3L * C_ * FC_);
  out[i] = (half_t)in[((l * FC_ + f) * C_ + c) * 3 + k];
}
__global__ void cvt_w2(const float* in, half_t* out) {  // [L][C][FC][3] -> [L][3][C][FC]
  long i = (long)blockIdx.x * 256 + threadIdx.x;
  const long n = (long)L_ * 3 * C_ * FC_;
  if (i >= n) return;
  long f = i % FC_, c = (i / FC_) % C_, k = (i / ((long)FC_ * C_)) % 3, l = i / (3L * FC_ * C_);
  out[i] = (half_t)in[((l * C_ + c) * FC_ + f) * 3 + k];
}
__global__ void zero_pads(half_t* xbf, half_t* hbf) {
  long i = (long)blockIdx.x * 256 + threadIdx.x;
  const long nx = (long)B_ * 2 * C_, nh = (long)B_ * 2 * FC_;
  if (i < nx) {
    long b = i / (2 * C_), r = (i / C_) % 2, c = i % C_;
    xbf[(b * TP_ + (r ? TP_ - 1 : 0)) * C_ + c] = (half_t)0.f;
  } else if (i < nx + nh) {
    long j = i - nx;
    long b = j / (2 * FC_), r = (j / FC_) % 2, f = j % FC_;
    hbf[(b * TP_ + (r ? TP_ - 1 : 0)) * FC_ + f] = (half_t)0.f;
  }
}

// ---------------- host orchestration ----------------
extern "C" void kernel_launch(void* const* d_in, const int* in_sizes, int n_in,
                              void* d_out, int out_size, void* d_ws, size_t ws_size,
                              hipStream_t stream) {
  if ((long)ws_size < WS_NEED) return;

  const float* x_in = (const float*)d_in[0];
  const float* mask = (const float*)d_in[1];
  const float* Wq = (const float*)d_in[2];  const float* bq = (const float*)d_in[3];
  const float* Wk = (const float*)d_in[4];  const float* bk = (const float*)d_in[5];
  const float* Wv = (const float*)d_in[6];  const float* bv = (const float*)d_in[7];
  const float* Wo = (const float*)d_in[8];  const float* bo = (const float*)d_in[9];
  const float* erk = (const float*)d_in[10];
  const float* erv = (const float*)d_in[11];
  const float* W1 = (const float*)d_in[12]; const float* b1 = (const float*)d_in[13];
  const float* W2 = (const float*)d_in[14]; const float* b2 = (const float*)d_in[15];
  const float* g1 = (const float*)d_in[16]; const float* be1 = (const float*)d_in[17];
  const float* g2 = (const float*)d_in[18]; const float* be2 = (const float*)d_in[19];

  char* w = (char*)d_ws;
  half_t* wqkv_h = (half_t*)(w + O_WQKV);
  half_t* wo_h = (half_t*)(w + O_WO);
  half_t* w1_h = (half_t*)(w + O_W1);
  half_t* w2_h = (half_t*)(w + O_W2);
  float*  bqkv = (float*)(w + O_BQ);
  half_t* x_h  = (half_t*)(w + O_X);
  half_t* q_h  = (half_t*)(w + O_Q);
  half_t* k_h  = (half_t*)(w + O_K);
  half_t* at_h = (half_t*)(w + O_ATT);
  half_t* vt_h = (half_t*)(w + O_VT);
  half_t* h_h  = (half_t*)(w + O_H);
  half_t* p_h  = (half_t*)(w + O_P);
  float*  xw   = (float*)(w + O_XW);
  float*  yb   = (float*)(w + O_Y);

  const long NWQ = (long)L_ * QKV_ * C_;
  const long NWO = (long)L_ * C_ * C_;
  const long NW1 = (long)L_ * 3 * FC_ * C_;
  cvt_wqkv<<<dim3((NWQ + 255) / 256), 256, 0, stream>>>(Wq, Wk, Wv, wqkv_h);
  cvt_bqkv<<<dim3(((long)L_ * QKV_ + 255) / 256), 256, 0, stream>>>(bq, bk, bv, bqkv);
  cvt_f2h<<<dim3((NWO + 255) / 256), 256, 0, stream>>>(Wo, wo_h, NWO);
  cvt_w1<<<dim3((NW1 + 255) / 256), 256, 0, stream>>>(W1, w1_h);
  cvt_w2<<<dim3((NW1 + 255) / 256), 256, 0, stream>>>(W2, w2_h);
  transpose_in<<<dim3(16, 24, 8), dim3(32, 8), 0, stream>>>(x_in, mask, xw, x_h);
  zero_pads<<<dim3((B_ * 2 * (C_ + FC_) + 255) / 256), 256, 0, stream>>>(x_h, h_h);

  for (int l = 0; l < L_; ++l) {
    GemmArgs a;
    a.out2 = nullptr; a.out3 = nullptr; a.sPart = 0;

    // ---- fused QKV projection (Q pre-scaled), epilogue routes q/k/v ----
    a.A = x_h; a.lda = C_; a.rowA = 1; a.sAz = (long)TP_ * C_; a.sAh = 0;
    a.B = wqkv_h + (long)l * QKV_ * C_; a.ldb = C_; a.rowB = 0; a.sBz = 0; a.sBh = 0; a.sBs = 0;
    a.Kc = C_; a.nshift = 1; a.ksplit = 1; a.bias = bqkv + (long)l * QKV_; a.relu = 0;
    a.out = (void*)q_h; a.out2 = (void*)k_h; a.out3 = (void*)vt_h;
    a.mode = 3; a.ldo = 0; a.sOz = 0; a.sOh = 0;
    a.hdiv = 1; a.nlim = QKV_;
    gemm_nt<<<dim3(4, 18, 8), 256, 0, stream>>>(a);

    // ---- scores = qs k^T per (b,h) ----
    a.A = q_h; a.lda = C_; a.rowA = 1; a.sAz = (long)TP_ * C_; a.sAh = 64;
    a.B = k_h; a.ldb = C_; a.rowB = 1; a.sBz = (long)TP_ * C_; a.sBh = 64; a.sBs = 0;
    a.Kc = 64; a.nshift = 1; a.ksplit = 1; a.bias = nullptr; a.relu = 0;
    a.out = (void*)p_h; a.mode = 1; a.ldo = T_;
    a.sOz = (long)H_ * T_ * T_; a.sOh = (long)T_ * T_; a.sPart = 0;
    a.hdiv = H_; a.nlim = T_;
    gemm_nt<<<dim3(4, 4, 96), 256, 0, stream>>>(a);

    softmax_rel<<<dim3(512, 12, 8), 256, 0, stream>>>(p_h, q_h, erk);

    // ---- out = p @ v per (b,h), split-K=2, fp32 partials ----
    a.A = p_h; a.lda = T_; a.rowA = 0; a.sAz = (long)H_ * T_ * T_; a.sAh = (long)T_ * T_;
    a.B = vt_h; a.ldb = T_; a.rowB = 0; a.sBz = (long)C_ * T_; a.sBh = 64L * T_; a.sBs = 0;
    a.Kc = T_; a.nshift = 1; a.ksplit = 2; a.bias = nullptr; a.relu = 0;
    a.out = (void*)yb; a.mode = 0; a.ldo = C_;
    a.sOz = (long)T_ * C_; a.sOh = 64; a.sPart = SLAB;
    a.hdiv = H_; a.nlim = 64;
    gemm_nt<<<dim3(4, 1, 192), 256, 0, stream>>>(a);

    add_rel_v<<<dim3(128, 12, 8), 256, 0, stream>>>(at_h, yb, p_h, erv);

    // ---- Wo projection, split-K=4, fp32 partials ----
    a.A = at_h; a.lda = C_; a.rowA = 1; a.sAz = (long)TP_ * C_; a.sAh = 0;
    a.B = wo_h + (long)l * C_ * C_; a.ldb = C_; a.rowB = 0; a.sBz = 0; a.sBh = 0; a.sBs = 0;
    a.Kc = C_; a.nshift = 1; a.ksplit = 4; a.bias = bo + (long)l * C_; a.relu = 0;
    a.out = (void*)yb; a.mode = 0; a.ldo = C_; a.sOz = (long)T_ * C_; a.sOh = 0; a.sPart = SLAB;
    a.hdiv = 1; a.nlim = C_;
    gemm_nt<<<dim3(4, 6, 32), 256, 0, stream>>>(a);

    ln_res<<<dim3(B_ * T_), 256, 0, stream>>>(xw, yb, g1 + (long)l * C_, be1 + (long)l * C_, x_h);

    // ---- conv FFN layer 1 (3-shift fused GEMM, relu) ----
    a.A = x_h; a.lda = C_; a.rowA = 0; a.sAz = (long)TP_ * C_; a.sAh = 0;
    a.B = w1_h + (long)l * 3 * FC_ * C_; a.ldb = C_; a.rowB = 0; a.sBz = 0; a.sBh = 0;
    a.sBs = (long)FC_ * C_;
    a.Kc = C_; a.nshift = 3; a.ksplit = 1; a.bias = b1 + (long)l * FC_; a.relu = 1;
    a.out = (void*)(h_h + FC_); a.mode = 1; a.ldo = FC_; a.sOz = (long)TP_ * FC_; a.sOh = 0; a.sPart = 0;
    a.hdiv = 1; a.nlim = FC_;
    gemm_nt<<<dim3(4, 24, 8), 256, 0, stream>>>(a);

    // ---- conv FFN layer 2, split-K=4, fp32 partials ----
    a.A = h_h; a.lda = FC_; a.rowA = 0; a.sAz = (long)TP_ * FC_; a.sAh = 0;
    a.B = w2_h + (long)l * 3 * C_ * FC_; a.ldb = FC_; a.rowB = 0; a.sBz = 0; a.sBh = 0;
    a.sBs = (long)C_ * FC_;
    a.Kc = FC_; a.nshift = 3; a.ksplit = 4; a.bias = b2 + (long)l * C_; a.relu = 0;
    a.out = (void*)yb; a.mode = 0; a.ldo = C_; a.sOz = (long)T_ * C_; a.sOh = 0; a.sPart = SLAB;
    a.hdiv = 1; a.nlim = C_;
    gemm_nt<<<dim3(4, 6, 32), 256, 0, stream>>>(a);

    ln_res<<<dim3(B_ * T_), 256, 0, stream>>>(xw, yb, g2 + (long)l * C_, be2 + (long)l * C_, x_h);
  }

  transpose_out<<<dim3(16, 24, 8), dim3(32, 8), 0, stream>>>(xw, mask, (float*)d_out);
}

// Round 3
// 2524.487 us; speedup vs baseline: 1.6433x; 1.2324x over previous
//
#include <hip/hip_runtime.h>
#include <stdint.h>

// ---------------- problem constants ----------------
#define L_  6
#define B_  8
#define T_  512
#define C_  768
#define FC_ 3072
#define H_  12
#define DK_ 64
#define TP_ 514   // T + 2 zero-pad rows (row r holds token r-1)
#define QKV_ (3 * C_)

typedef _Float16 half_t;
typedef half_t f16x8 __attribute__((ext_vector_type(8)));
typedef float  f32x4 __attribute__((ext_vector_type(4)));

static constexpr long alg(long x) { return (x + 255) & ~255L; }
constexpr long SLAB = (long)B_ * T_ * C_;   // fp32 partial slab elements

// ---------------- workspace layout (bytes) ----------------
constexpr long SZ_WQKV_B = (long)L_ * QKV_ * C_ * 2;
constexpr long SZ_WO_B   = (long)L_ * C_ * C_ * 2;
constexpr long SZ_W1_B   = (long)L_ * 3 * FC_ * C_ * 2;  // repacked [L][3][FC][C]
constexpr long SZ_BQ_B   = (long)L_ * QKV_ * 4;
constexpr long SZ_ACT_B  = (long)B_ * TP_ * C_ * 2;
constexpr long SZ_VT_B   = ((long)B_ * C_ * T_ + 65536) * 2;
constexpr long SZ_H_B    = (long)B_ * TP_ * FC_ * 2;
constexpr long SZ_ML_B   = 2L * B_ * H_ * T_ * 4;        // m,l per attention row
constexpr long SZ_XW_B   = SLAB * 4;
constexpr long SZ_Y_B    = 4 * SLAB * 4;                 // 4 fp32 partial slabs

constexpr long O_WQKV = 0;
constexpr long O_WO  = O_WQKV + alg(SZ_WQKV_B);
constexpr long O_W1  = O_WO   + alg(SZ_WO_B);
constexpr long O_W2  = O_W1   + alg(SZ_W1_B);
constexpr long O_BQ  = O_W2   + alg(SZ_W1_B);
constexpr long O_X   = O_BQ   + alg(SZ_BQ_B);
constexpr long O_Q   = O_X    + alg(SZ_ACT_B);
constexpr long O_K   = O_Q    + alg(SZ_ACT_B);
constexpr long O_ATT = O_K    + alg(SZ_ACT_B);
constexpr long O_VT  = O_ATT  + alg(SZ_ACT_B);
constexpr long O_H   = O_VT   + alg(SZ_VT_B);
constexpr long O_ML  = O_H    + alg(SZ_H_B);
constexpr long O_XW  = O_ML   + alg(SZ_ML_B);
constexpr long O_Y   = O_XW   + alg(SZ_XW_B);
constexpr long WS_NEED = O_Y + alg(SZ_Y_B);

// ---------------- async global->LDS (16B/lane, wave-uniform LDS base) ----------------
__device__ __forceinline__ void async_ld16(half_t* lds, const half_t* g) {
  __builtin_amdgcn_global_load_lds(
      (const __attribute__((address_space(1))) void*)g,
      (__attribute__((address_space(3))) void*)lds,
      16, 0, 0);
}

// ---------------- generic NT GEMM, 128x128 tile, BK=32, fp16 MFMA, split-K ----------------
struct GemmArgs {
  const half_t* A; const half_t* B; const float* bias;
  void* out; void* out2; void* out3;
  long lda, ldb, ldo;
  long sAz, sAh, sBz, sBh, sBs, sOz, sOh, sPart;
  int hdiv, rowA, rowB, Kc, nshift, ksplit, mode, relu, nlim;
};

__global__ __launch_bounds__(256) void gemm_nt(GemmArgs g) {
  __shared__ half_t As[128 * 32];
  __shared__ half_t Bs[128 * 32];
  const int tid  = threadIdx.x;
  const int lane = tid & 63;
  const int wv   = tid >> 6;
  const int wm   = (wv >> 1) * 64;
  const int wn   = (wv & 1) * 64;
  const int zz   = blockIdx.z;
  const int ks   = zz % g.ksplit;
  const int z    = zz / g.ksplit;
  const int bz   = z / g.hdiv, hz = z % g.hdiv;
  const half_t* Ab = g.A + (long)bz * g.sAz + (long)hz * g.sAh;
  const half_t* Bb = g.B + (long)bz * g.sBz + (long)hz * g.sBh;
  const long m0 = (long)blockIdx.x * 128;
  const long n0 = (long)blockIdx.y * 128;

  const int srow = lane >> 2;
  const int scol = ((((lane & 3) - (srow & 3)) & 3)) * 8;
  half_t* AsW = As + wv * 1024;
  half_t* BsW = Bs + wv * 1024;

  f32x4 acc[4][4];
#pragma unroll
  for (int i = 0; i < 4; ++i)
#pragma unroll
    for (int j = 0; j < 4; ++j) acc[i][j] = f32x4{0.f, 0.f, 0.f, 0.f};

  const int nkb = g.Kc >> 5;
  const int nIter = g.nshift * nkb;
  const int chunk = (nIter + g.ksplit - 1) / g.ksplit;
  int it = ks * chunk;
  const int itEnd0 = it + chunk;
  const int itEnd = itEnd0 < nIter ? itEnd0 : nIter;

  const int kqr = lane >> 4;
  while (it < itEnd) {
    const int s = it / nkb;
    int kbi = it - s * nkb;
    int kbiEnd = kbi + (itEnd - it);
    if (kbiEnd > nkb) kbiEnd = nkb;
    it += kbiEnd - kbi;
    const half_t* Arow = Ab + ((long)(g.rowA + s) + m0) * g.lda;
    const half_t* Brow = Bb + (long)s * g.sBs + (g.rowB + n0) * g.ldb;
    for (; kbi < kbiEnd; ++kbi) {
      const int kb = kbi << 5;
#pragma unroll
      for (int i = 0; i < 2; ++i) {
        async_ld16(AsW + i * 512,
                   Arow + (long)(wv * 32 + i * 16 + srow) * g.lda + kb + scol);
        async_ld16(BsW + i * 512,
                   Brow + (long)(wv * 32 + i * 16 + srow) * g.ldb + kb + scol);
      }
      __syncthreads();
      f16x8 af[4], bfr[4];
#pragma unroll
      for (int f = 0; f < 4; ++f) {
        int rA = wm + f * 16 + (lane & 15);
        int rB = wn + f * 16 + (lane & 15);
        af[f]  = *(const f16x8*)(As + (rA >> 5) * 1024 + (rA & 31) * 32 + ((kqr + rA) & 3) * 8);
        bfr[f] = *(const f16x8*)(Bs + (rB >> 5) * 1024 + (rB & 31) * 32 + ((kqr + rB) & 3) * 8);
      }
#pragma unroll
      for (int fm = 0; fm < 4; ++fm)
#pragma unroll
        for (int fn = 0; fn < 4; ++fn)
          acc[fm][fn] = __builtin_amdgcn_mfma_f32_16x16x32_f16(af[fm], bfr[fn], acc[fm][fn], 0, 0, 0);
      __syncthreads();
    }
  }

  const int col = lane & 15, quad = lane >> 4;
  const long obase = (long)bz * g.sOz + (long)hz * g.sOh + (long)ks * g.sPart;
#pragma unroll
  for (int fm = 0; fm < 4; ++fm) {
#pragma unroll
    for (int fn = 0; fn < 4; ++fn) {
      int n = (int)n0 + wn + fn * 16 + col;
      if (n >= g.nlim) continue;
      float bia = (g.bias && ks == 0) ? g.bias[n] : 0.f;
#pragma unroll
      for (int i = 0; i < 4; ++i) {
        long m = m0 + wm + fm * 16 + quad * 4 + i;
        float v = acc[fm][fn][i] + bia;
        if (g.relu) v = fmaxf(v, 0.f);
        if (g.mode == 0) {
          ((float*)g.out)[obase + m * g.ldo + n] = v;
        } else if (g.mode == 1) {
          ((half_t*)g.out)[obase + m * g.ldo + n] = (half_t)v;
        } else {  // mode 3: fused QKV router
          int seg = n / C_, nn = n - seg * C_;
          if (seg == 2)
            ((half_t*)g.out3)[((long)bz * C_ + nn) * T_ + m] = (half_t)v;
          else {
            half_t* dstb = seg ? (half_t*)g.out2 : (half_t*)g.out;
            dstb[((long)bz * TP_ + 1 + m) * C_ + nn] = (half_t)v;
          }
        }
      }
    }
  }
}

// ---------------- fused flash attention with banded rel-k logits ----------------
// grid (T/128, H, B), 256 thr. Wave w owns Q rows [q0+w*32, q0+w*32+32).
// Writes O (normalized, fp16, token-major) + per-row m,l for the band kernel.
__global__ __launch_bounds__(256) void attn_fused(
    const half_t* __restrict__ q, const half_t* __restrict__ k,
    const half_t* __restrict__ vt, const float* __restrict__ erk,
    half_t* __restrict__ attn, float* __restrict__ m_ws, float* __restrict__ l_ws) {
  __shared__ half_t Ks[128 * 64];      // [s 128][k 64], 8 swizzled 16B slots/row
  __shared__ half_t Vs[64 * 128];      // [d 64][s 128], 16 swizzled slots/row
  __shared__ half_t Ps[4][32 * 132];   // per-wave P strip, 264B padded rows
  __shared__ float  rl[4][32][12];     // per-wave banded rel-k logits

  const int tid = threadIdx.x, lane = tid & 63, w = tid >> 6;
  const int h = blockIdx.y, b = blockIdx.z;
  const int q0 = blockIdx.x * 128;
  const int l15 = lane & 15, quad = lane >> 4;
  const long hbase = ((long)b * TP_ + 1) * C_ + h * 64;  // + t*C_ for token t

  // ---- Q a-frags (q pre-scaled by 1/sqrt(dk)) ----
  f16x8 qa[2][2];
#pragma unroll
  for (int fm = 0; fm < 2; ++fm)
#pragma unroll
    for (int kf = 0; kf < 2; ++kf) {
      int t = q0 + w * 32 + fm * 16 + l15;
      qa[fm][kf] = *(const f16x8*)(q + hbase + (long)t * C_ + kf * 32 + quad * 8);
    }

  // ---- rl[row][r] = qs[row] . erk[r] via 4 MFMAs ----
  {
    f16x8 eb[2];
#pragma unroll
    for (int kf = 0; kf < 2; ++kf) {
      f16x8 e;
#pragma unroll
      for (int j = 0; j < 8; ++j)
        e[j] = (half_t)(l15 < 9 ? erk[l15 * 64 + kf * 32 + quad * 8 + j] : 0.f);
      eb[kf] = e;
    }
#pragma unroll
    for (int fm = 0; fm < 2; ++fm) {
      f32x4 a = f32x4{0.f, 0.f, 0.f, 0.f};
      a = __builtin_amdgcn_mfma_f32_16x16x32_f16(qa[fm][0], eb[0], a, 0, 0, 0);
      a = __builtin_amdgcn_mfma_f32_16x16x32_f16(qa[fm][1], eb[1], a, 0, 0, 0);
      if (l15 < 9)
#pragma unroll
        for (int i = 0; i < 4; ++i)
          rl[w][fm * 16 + quad * 4 + i][l15] = a[i];
    }
  }

  float mst[2][4], lst[2][4];
  f32x4 Oa[2][4];
#pragma unroll
  for (int fm = 0; fm < 2; ++fm)
#pragma unroll
    for (int i = 0; i < 4; ++i) { mst[fm][i] = -1e30f; lst[fm][i] = 0.f; }
#pragma unroll
  for (int fm = 0; fm < 2; ++fm)
#pragma unroll
    for (int fn = 0; fn < 4; ++fn) Oa[fm][fn] = f32x4{0.f, 0.f, 0.f, 0.f};

  for (int kt = 0; kt < 4; ++kt) {
    const int s0 = kt * 128;
    __syncthreads();   // prior tile's K/V reads done before restage
    // stage K tile: wave w rows [w*32, w*32+32)
#pragma unroll
    for (int i = 0; i < 4; ++i) {
      int row = w * 32 + i * 8 + (lane >> 3);
      int sl = ((lane & 7) - row) & 7;
      async_ld16(Ks + (w * 32 + i * 8) * 64,
                 k + hbase + (long)(s0 + row) * C_ + sl * 8);
    }
    // stage V tile (transposed source): wave w dims [w*16, w*16+16)
#pragma unroll
    for (int i = 0; i < 4; ++i) {
      int d = w * 16 + i * 4 + (lane >> 4);
      int sl = ((lane & 15) - d) & 15;
      async_ld16(Vs + (w * 16 + i * 4) * 128,
                 vt + ((long)b * C_ + h * 64 + d) * T_ + s0 + sl * 8);
    }
    __syncthreads();

    // ---- S = Qs K^T ----
    f32x4 Sa[2][8];
#pragma unroll
    for (int fm = 0; fm < 2; ++fm)
#pragma unroll
      for (int fn = 0; fn < 8; ++fn) Sa[fm][fn] = f32x4{0.f, 0.f, 0.f, 0.f};
#pragma unroll
    for (int ks = 0; ks < 2; ++ks)
#pragma unroll
      for (int fn = 0; fn < 8; ++fn) {
        int row = fn * 16 + l15;
        int p = ((ks * 4 + quad) + row) & 7;
        f16x8 bf = *(const f16x8*)(Ks + row * 64 + p * 8);
        Sa[0][fn] = __builtin_amdgcn_mfma_f32_16x16x32_f16(qa[0][ks], bf, Sa[0][fn], 0, 0, 0);
        Sa[1][fn] = __builtin_amdgcn_mfma_f32_16x16x32_f16(qa[1][ks], bf, Sa[1][fn], 0, 0, 0);
      }

    // ---- banded rel-k add ----
#pragma unroll
    for (int fm = 0; fm < 2; ++fm) {
      int rbase = q0 + w * 32 + fm * 16;
#pragma unroll
      for (int fn = 0; fn < 8; ++fn) {
        int db = s0 + fn * 16 - rbase + 4;
        if (db < -15 || db > 23) continue;   // frag outside band
#pragma unroll
        for (int i = 0; i < 4; ++i) {
          int d = db + l15 - quad * 4 - i;
          if (d >= 0 && d < 9)
            Sa[fm][fn][i] += rl[w][fm * 16 + quad * 4 + i][d];
        }
      }
    }

    // ---- online softmax (rows private to this wave's quad groups) ----
#pragma unroll
    for (int fm = 0; fm < 2; ++fm) {
      float tmax[4] = {-1e30f, -1e30f, -1e30f, -1e30f};
#pragma unroll
      for (int fn = 0; fn < 8; ++fn)
#pragma unroll
        for (int i = 0; i < 4; ++i) tmax[i] = fmaxf(tmax[i], Sa[fm][fn][i]);
#pragma unroll
      for (int i = 0; i < 4; ++i) {
#pragma unroll
        for (int off = 1; off < 16; off <<= 1)
          tmax[i] = fmaxf(tmax[i], __shfl_xor(tmax[i], off));
      }
      float alpha[4], rsum[4];
#pragma unroll
      for (int i = 0; i < 4; ++i) {
        float mn = fmaxf(mst[fm][i], tmax[i]);
        alpha[i] = __expf(mst[fm][i] - mn);
        mst[fm][i] = mn;
        rsum[i] = 0.f;
      }
#pragma unroll
      for (int fn = 0; fn < 8; ++fn)
#pragma unroll
        for (int i = 0; i < 4; ++i) {
          float e = __expf(Sa[fm][fn][i] - mst[fm][i]);
          rsum[i] += e;
          Ps[w][(fm * 16 + quad * 4 + i) * 132 + fn * 16 + l15] = (half_t)e;
        }
#pragma unroll
      for (int i = 0; i < 4; ++i) {
#pragma unroll
        for (int off = 1; off < 16; off <<= 1) rsum[i] += __shfl_xor(rsum[i], off);
        lst[fm][i] = lst[fm][i] * alpha[i] + rsum[i];
#pragma unroll
        for (int fn2 = 0; fn2 < 4; ++fn2) Oa[fm][fn2][i] *= alpha[i];
      }
    }

    // ---- O += P V (P strip private; in-wave lgkmcnt orders write->read) ----
#pragma unroll
    for (int ks2 = 0; ks2 < 4; ++ks2) {
      f16x8 pa[2];
#pragma unroll
      for (int fm = 0; fm < 2; ++fm)
        pa[fm] = *(const f16x8*)(&Ps[w][(fm * 16 + l15) * 132 + ks2 * 32 + quad * 8]);
#pragma unroll
      for (int fn2 = 0; fn2 < 4; ++fn2) {
        int d = fn2 * 16 + l15;
        int p = ((ks2 * 4 + quad) + d) & 15;
        f16x8 bv = *(const f16x8*)(Vs + d * 128 + p * 8);
        Oa[0][fn2] = __builtin_amdgcn_mfma_f32_16x16x32_f16(pa[0], bv, Oa[0][fn2], 0, 0, 0);
        Oa[1][fn2] = __builtin_amdgcn_mfma_f32_16x16x32_f16(pa[1], bv, Oa[1][fn2], 0, 0, 0);
      }
    }
  }

  // ---- epilogue: normalize, store O + m,l ----
  const long mlbase = ((long)b * H_ + h) * T_;
#pragma unroll
  for (int fm = 0; fm < 2; ++fm)
#pragma unroll
    for (int i = 0; i < 4; ++i) {
      int t = q0 + w * 32 + fm * 16 + quad * 4 + i;
      float inv = 1.f / lst[fm][i];
      if (l15 == 0) { m_ws[mlbase + t] = mst[fm][i]; l_ws[mlbase + t] = lst[fm][i]; }
#pragma unroll
      for (int fn2 = 0; fn2 < 4; ++fn2)
        attn[hbase + (long)t * C_ + fn2 * 16 + l15] = (half_t)(Oa[fm][fn2][i] * inv);
    }
}

// ---------------- banded p @ rel_v add (recomputes 9 band probs from m,l) ----------------
__global__ __launch_bounds__(256) void band_rel_v(
    half_t* attn, const half_t* q, const half_t* k, const float* erk,
    const float* erv, const float* m_ws, const float* l_ws) {
  const int w = threadIdx.x >> 6, lane = threadIdx.x & 63;
  const int t = blockIdx.x * 4 + w, h = blockIdx.y, b = blockIdx.z;
  const long base = ((long)b * TP_ + 1 + t) * C_ + h * 64 + lane;
  const float qv = (float)q[base];
  const long ml = ((long)b * H_ + h) * T_ + t;
  const float m = m_ws[ml];
  const float inv = 1.f / l_ws[ml];
  float acc = 0.f;
#pragma unroll
  for (int r = 0; r < 9; ++r) {
    int s = t + r - 4;
    if (s < 0 || s >= T_) continue;
    float kv = (float)k[((long)b * TP_ + 1 + s) * C_ + h * 64 + lane];
    float dot = qv * (kv + erk[r * 64 + lane]);
#pragma unroll
    for (int off = 32; off; off >>= 1) dot += __shfl_xor(dot, off);
    acc += __expf(dot - m) * inv * erv[r * 64 + lane];
  }
  attn[base] = (half_t)((float)attn[base] + acc);
}

// ---------------- 4-partial reduce + residual + LayerNorm ----------------
__global__ __launch_bounds__(256) void ln_res(float* xw, const float* yb,
                                              const float* gamma, const float* beta, half_t* xbf) {
  __shared__ float redA[4], redB[4];
  const int row = blockIdx.x;
  const int b = row >> 9, t = row & 511;
  const long base = (long)row * C_;
  float v[3]; float sum = 0.f, sq = 0.f;
#pragma unroll
  for (int i = 0; i < 3; ++i) {
    int c = threadIdx.x + i * 256;
    float s = xw[base + c];
#pragma unroll
    for (int j = 0; j < 4; ++j) s += yb[j * SLAB + base + c];
    v[i] = s; sum += s; sq += s * s;
  }
#pragma unroll
  for (int off = 32; off; off >>= 1) { sum += __shfl_xor(sum, off); sq += __shfl_xor(sq, off); }
  const int w = threadIdx.x >> 6;
  if ((threadIdx.x & 63) == 0) { redA[w] = sum; redB[w] = sq; }
  __syncthreads();
  sum = redA[0] + redA[1] + redA[2] + redA[3];
  sq  = redB[0] + redB[1] + redB[2] + redB[3];
  float mean = sum * (1.f / C_);
  float var  = sq * (1.f / C_) - mean * mean;
  float rstd = rsqrtf(var + 1e-5f);
  const long bb = ((long)b * TP_ + t + 1) * C_;
#pragma unroll
  for (int i = 0; i < 3; ++i) {
    int c = threadIdx.x + i * 256;
    float o = (v[i] - mean) * rstd * gamma[c] + beta[c];
    xw[base + c] = o;
    xbf[bb + c] = (half_t)o;
  }
}

// ---------------- transposes in/out ----------------
__global__ __launch_bounds__(256) void transpose_in(const float* xin, const float* mask,
                                                    float* xw, half_t* xbf) {
  __shared__ float tl[32][33];
  const int b = blockIdx.z, t0 = blockIdx.x * 32, c0 = blockIdx.y * 32;
  const int tx = threadIdx.x, ty = threadIdx.y;
#pragma unroll
  for (int j = 0; j < 4; ++j) {
    int c = c0 + ty + j * 8;
    tl[ty + j * 8][tx] = xin[((long)b * C_ + c) * T_ + t0 + tx] * mask[(long)b * T_ + t0 + tx];
  }
  __syncthreads();
#pragma unroll
  for (int j = 0; j < 4; ++j) {
    int t = t0 + ty + j * 8;
    float v = tl[tx][ty + j * 8];
    xw[((long)b * T_ + t) * C_ + c0 + tx] = v;
    xbf[((long)b * TP_ + t + 1) * C_ + c0 + tx] = (half_t)v;
  }
}

__global__ __launch_bounds__(256) void transpose_out(const float* xw, const float* mask, float* out) {
  __shared__ float tl[32][33];
  const int b = blockIdx.z, t0 = blockIdx.x * 32, c0 = blockIdx.y * 32;
  const int tx = threadIdx.x, ty = threadIdx.y;
#pragma unroll
  for (int j = 0; j < 4; ++j) {
    int t = t0 + ty + j * 8;
    tl[ty + j * 8][tx] = xw[((long)b * T_ + t) * C_ + c0 + tx];
  }
  __syncthreads();
#pragma unroll
  for (int j = 0; j < 4; ++j) {
    int c = c0 + ty + j * 8;
    out[((long)b * C_ + c) * T_ + t0 + tx] = tl[tx][ty + j * 8] * mask[(long)b * T_ + t0 + tx];
  }
}

// ---------------- weight conversion / repack ----------------
__global__ void cvt_f2h(const float* in, half_t* out, long n) {
  long i = (long)blockIdx.x * 256 + threadIdx.x;
  if (i < n) out[i] = (half_t)in[i];
}
__global__ void cvt_wqkv(const float* wq, const float* wk, const float* wv, half_t* out) {
  long i = (long)blockIdx.x * 256 + threadIdx.x;
  const long n = (long)L_ * QKV_ * C_;
  if (i >= n) return;
  long c = i % C_, o = (i / C_) % QKV_, l = i / ((long)QKV_ * C_);
  int seg = (int)(o / C_); long oo = o - (long)seg * C_;
  const float* src = seg == 0 ? wq : (seg == 1 ? wk : wv);
  float v = src[(l * C_ + oo) * C_ + c];
  out[i] = (half_t)(seg == 0 ? v * 0.125f : v);
}
__global__ void cvt_bqkv(const float* bq, const float* bk, const float* bv, float* out) {
  long i = (long)blockIdx.x * 256 + threadIdx.x;
  const long n = (long)L_ * QKV_;
  if (i >= n) return;
  long o = i % QKV_, l = i / QKV_;
  int seg = (int)(o / C_); long oo = o - (long)seg * C_;
  const float* src = seg == 0 ? bq : (seg == 1 ? bk : bv);
  float v = src[l * C_ + oo];
  out[i] = seg == 0 ? v * 0.125f : v;
}
__global__ void cvt_w1(const float* in, half_t* out) {  // [L][FC][C][3] -> [L][3][FC][C]
  long i = (long)blockIdx.x * 256 + threadIdx.x;
  const long n = (long)L_ * 3 * FC_ * C_;
  if (i >= n) return;
  long c = i % C_, f = (i / C_) % FC_, k = (i / ((long)C_ * FC_)) % 3, l = i / (3L * C_ * FC_);
  out[i] = (half_t)in[((l * FC_ + f) * C_ + c) * 3 + k];
}
__global__ void cvt_w2(const float* in, half_t* out) {  // [L][C][FC][3] -> [L][3][C][FC]
  long i = (long)blockIdx.x * 256 + threadIdx.x;
  const long n = (long)L_ * 3 * C_ * FC_;
  if (i >= n) return;
  long f = i % FC_, c = (i / FC_) % C_, k = (i / ((long)FC_ * C_)) % 3, l = i / (3L * FC_ * C_);
  out[i] = (half_t)in[((l * C_ + c) * FC_ + f) * 3 + k];
}
__global__ void zero_pads(half_t* xbf, half_t* hbf) {
  long i = (long)blockIdx.x * 256 + threadIdx.x;
  const long nx = (long)B_ * 2 * C_, nh = (long)B_ * 2 * FC_;
  if (i < nx) {
    long b = i / (2 * C_), r = (i / C_) % 2, c = i % C_;
    xbf[(b * TP_ + (r ? TP_ - 1 : 0)) * C_ + c] = (half_t)0.f;
  } else if (i < nx + nh) {
    long j = i - nx;
    long b = j / (2 * FC_), r = (j / FC_) % 2, f = j % FC_;
    hbf[(b * TP_ + (r ? TP_ - 1 : 0)) * FC_ + f] = (half_t)0.f;
  }
}

// ---------------- host orchestration ----------------
extern "C" void kernel_launch(void* const* d_in, const int* in_sizes, int n_in,
                              void* d_out, int out_size, void* d_ws, size_t ws_size,
                              hipStream_t stream) {
  if ((long)ws_size < WS_NEED) return;

  const float* x_in = (const float*)d_in[0];
  const float* mask = (const float*)d_in[1];
  const float* Wq = (const float*)d_in[2];  const float* bq = (const float*)d_in[3];
  const float* Wk = (const float*)d_in[4];  const float* bk = (const float*)d_in[5];
  const float* Wv = (const float*)d_in[6];  const float* bv = (const float*)d_in[7];
  const float* Wo = (const float*)d_in[8];  const float* bo = (const float*)d_in[9];
  const float* erk = (const float*)d_in[10];
  const float* erv = (const float*)d_in[11];
  const float* W1 = (const float*)d_in[12]; const float* b1 = (const float*)d_in[13];
  const float* W2 = (const float*)d_in[14]; const float* b2 = (const float*)d_in[15];
  const float* g1 = (const float*)d_in[16]; const float* be1 = (const float*)d_in[17];
  const float* g2 = (const float*)d_in[18]; const float* be2 = (const float*)d_in[19];

  char* w = (char*)d_ws;
  half_t* wqkv_h = (half_t*)(w + O_WQKV);
  half_t* wo_h = (half_t*)(w + O_WO);
  half_t* w1_h = (half_t*)(w + O_W1);
  half_t* w2_h = (half_t*)(w + O_W2);
  float*  bqkv = (float*)(w + O_BQ);
  half_t* x_h  = (half_t*)(w + O_X);
  half_t* q_h  = (half_t*)(w + O_Q);
  half_t* k_h  = (half_t*)(w + O_K);
  half_t* at_h = (half_t*)(w + O_ATT);
  half_t* vt_h = (half_t*)(w + O_VT);
  half_t* h_h  = (half_t*)(w + O_H);
  float*  m_ws = (float*)(w + O_ML);
  float*  l_ws = m_ws + (long)B_ * H_ * T_;
  float*  xw   = (float*)(w + O_XW);
  float*  yb   = (float*)(w + O_Y);

  const long NWQ = (long)L_ * QKV_ * C_;
  const long NWO = (long)L_ * C_ * C_;
  const long NW1 = (long)L_ * 3 * FC_ * C_;
  cvt_wqkv<<<dim3((NWQ + 255) / 256), 256, 0, stream>>>(Wq, Wk, Wv, wqkv_h);
  cvt_bqkv<<<dim3(((long)L_ * QKV_ + 255) / 256), 256, 0, stream>>>(bq, bk, bv, bqkv);
  cvt_f2h<<<dim3((NWO + 255) / 256), 256, 0, stream>>>(Wo, wo_h, NWO);
  cvt_w1<<<dim3((NW1 + 255) / 256), 256, 0, stream>>>(W1, w1_h);
  cvt_w2<<<dim3((NW1 + 255) / 256), 256, 0, stream>>>(W2, w2_h);
  transpose_in<<<dim3(16, 24, 8), dim3(32, 8), 0, stream>>>(x_in, mask, xw, x_h);
  zero_pads<<<dim3((B_ * 2 * (C_ + FC_) + 255) / 256), 256, 0, stream>>>(x_h, h_h);

  for (int l = 0; l < L_; ++l) {
    GemmArgs a;
    a.out2 = nullptr; a.out3 = nullptr; a.sPart = 0;

    // ---- fused QKV projection (Q pre-scaled), epilogue routes q/k/v ----
    a.A = x_h; a.lda = C_; a.rowA = 1; a.sAz = (long)TP_ * C_; a.sAh = 0;
    a.B = wqkv_h + (long)l * QKV_ * C_; a.ldb = C_; a.rowB = 0; a.sBz = 0; a.sBh = 0; a.sBs = 0;
    a.Kc = C_; a.nshift = 1; a.ksplit = 1; a.bias = bqkv + (long)l * QKV_; a.relu = 0;
    a.out = (void*)q_h; a.out2 = (void*)k_h; a.out3 = (void*)vt_h;
    a.mode = 3; a.ldo = 0; a.sOz = 0; a.sOh = 0;
    a.hdiv = 1; a.nlim = QKV_;
    gemm_nt<<<dim3(4, 18, 8), 256, 0, stream>>>(a);

    // ---- fused flash attention (scores + banded rel-k + softmax + PV) ----
    attn_fused<<<dim3(4, H_, B_), 256, 0, stream>>>(q_h, k_h, vt_h, erk, at_h, m_ws, l_ws);

    // ---- banded p @ rel_v add ----
    band_rel_v<<<dim3(128, H_, B_), 256, 0, stream>>>(at_h, q_h, k_h, erk, erv, m_ws, l_ws);

    // ---- Wo projection, split-K=4, fp32 partials ----
    a.out2 = nullptr; a.out3 = nullptr;
    a.A = at_h; a.lda = C_; a.rowA = 1; a.sAz = (long)TP_ * C_; a.sAh = 0;
    a.B = wo_h + (long)l * C_ * C_; a.ldb = C_; a.rowB = 0; a.sBz = 0; a.sBh = 0; a.sBs = 0;
    a.Kc = C_; a.nshift = 1; a.ksplit = 4; a.bias = bo + (long)l * C_; a.relu = 0;
    a.out = (void*)yb; a.mode = 0; a.ldo = C_; a.sOz = (long)T_ * C_; a.sOh = 0; a.sPart = SLAB;
    a.hdiv = 1; a.nlim = C_;
    gemm_nt<<<dim3(4, 6, 32), 256, 0, stream>>>(a);

    ln_res<<<dim3(B_ * T_), 256, 0, stream>>>(xw, yb, g1 + (long)l * C_, be1 + (long)l * C_, x_h);

    // ---- conv FFN layer 1 (3-shift fused GEMM, relu) ----
    a.A = x_h; a.lda = C_; a.rowA = 0; a.sAz = (long)TP_ * C_; a.sAh = 0;
    a.B = w1_h + (long)l * 3 * FC_ * C_; a.ldb = C_; a.rowB = 0; a.sBz = 0; a.sBh = 0;
    a.sBs = (long)FC_ * C_;
    a.Kc = C_; a.nshift = 3; a.ksplit = 1; a.bias = b1 + (long)l * FC_; a.relu = 1;
    a.out = (void*)(h_h + FC_); a.mode = 1; a.ldo = FC_; a.sOz = (long)TP_ * FC_; a.sOh = 0; a.sPart = 0;
    a.hdiv = 1; a.nlim = FC_;
    gemm_nt<<<dim3(4, 24, 8), 256, 0, stream>>>(a);

    // ---- conv FFN layer 2, split-K=4, fp32 partials ----
    a.A = h_h; a.lda = FC_; a.rowA = 0; a.sAz = (long)TP_ * FC_; a.sAh = 0;
    a.B = w2_h + (long)l * 3 * C_ * FC_; a.ldb = FC_; a.rowB = 0; a.sBz = 0; a.sBh = 0;
    a.sBs = (long)C_ * FC_;
    a.Kc = FC_; a.nshift = 3; a.ksplit = 4; a.bias = b2 + (long)l * C_; a.relu = 0;
    a.out = (void*)yb; a.mode = 0; a.ldo = C_; a.sOz = (long)T_ * C_; a.sOh = 0; a.sPart = SLAB;
    a.hdiv = 1; a.nlim = C_;
    gemm_nt<<<dim3(4, 6, 32), 256, 0, stream>>>(a);

    ln_res<<<dim3(B_ * T_), 256, 0, stream>>>(xw, yb, g2 + (long)l * C_, be2 + (long)l * C_, x_h);
  }

  transpose_out<<<dim3(16, 24, 8), dim3(32, 8), 0, stream>>>(xw, mask, (float*)d_out);
}